// Round 2
// baseline (2165.725 us; speedup 1.0000x reference)
//
#include <hip/hip_runtime.h>
#include <hip/hip_bf16.h>

#define NTOK 8192      // B*S = 32*256
#define DD 16
#define VV 8192
#define VC 1024        // codes per LDS chunk
#define NCHUNK 8
#define TWG 32         // tokens per workgroup
#define G 8            // tokens per wave (per-thread register state)
#define KS 1.8033688011112042f  // log2(e)/0.8 (temperature fold)

// d_ws layout (float offsets)
#define WS_CBT 0        // cbT[16][8192]
#define WS_B1  131072   // b*KS
#define WS_T1  139264   // t_proj*KS
#define WS_CC2 147456   // ||c||^2
// total 155648 floats = 622592 bytes

__global__ __launch_bounds__(256) void prep_kernel(
    const float* __restrict__ cb, const float* __restrict__ bm,
    const float* __restrict__ tp, float* __restrict__ ws) {
  __shared__ float tile[256 * 17];   // +1 pad: conflict-free transpose
  float* cbT = ws + WS_CBT;
  float* B1  = ws + WS_B1;
  float* T1  = ws + WS_T1;
  float* CC2 = ws + WS_CC2;
  const int tid = threadIdx.x;
  const int v0 = blockIdx.x * 256;
#pragma unroll
  for (int k = 0; k < 4; k++) {
    int j = tid + (k << 8);          // float4 id in [0,1024)
    int v = j >> 2, d4 = (j & 3) << 2;
    float4 f = *(const float4*)(cb + (size_t)(v0 + v) * DD + d4);
    tile[v * 17 + d4 + 0] = f.x;
    tile[v * 17 + d4 + 1] = f.y;
    tile[v * 17 + d4 + 2] = f.z;
    tile[v * 17 + d4 + 3] = f.w;
  }
  __syncthreads();
#pragma unroll
  for (int k = 0; k < 16; k++) {
    int j = tid + (k << 8);
    int d = j >> 8, c = j & 255;
    cbT[(size_t)d * VV + v0 + c] = tile[c * 17 + d];
  }
  int v = v0 + tid;
  float s = 0.f;
#pragma unroll
  for (int d4 = 0; d4 < DD; d4 += 4) {
    float4 f = *(const float4*)(cb + (size_t)v * DD + d4);
    s += f.x * f.x + f.y * f.y + f.z * f.z + f.w * f.w;
  }
  CC2[v] = s;
  B1[v] = bm[v] * KS;
  T1[v] = tp[v] * KS;
}

__global__ __launch_bounds__(256, 1) void flow_kernel(
    const float* __restrict__ x0, const float* __restrict__ Wm,
    const float* __restrict__ ws, const int* __restrict__ nsp,
    float* __restrict__ out) {
  __shared__ float wL[DD * VC];     // 64 KB  W chunk, d-major
  __shared__ float cL[DD * VC];     // 64 KB  cbT chunk, d-major
  __shared__ float b1L[VC];
  __shared__ float t1L[VC];
  __shared__ float sL[TWG * DD];    // saved state s across midpoint halves

  const float* cbT = ws + WS_CBT;
  const float* B1  = ws + WS_B1;
  const float* T1  = ws + WS_T1;
  const float* CC2 = ws + WS_CC2;

  const int tid = threadIdx.x;
  const int lane = tid & 63;
  const int wave = tid >> 6;
  const int tokBase = blockIdx.x * TWG + wave * G;

  const int n_steps = *nsp;
  const float dt = 1.0f / (float)(n_steps - 1);

  float ex[G][DD];   // current eval state (x or xm) — all lanes replicate wave's 8 tokens
#pragma unroll
  for (int t = 0; t < G; t++) {
#pragma unroll
    for (int d4 = 0; d4 < DD; d4 += 4) {
      float4 f = *(const float4*)(x0 + (size_t)(tokBase + t) * DD + d4);
      ex[t][d4 + 0] = f.x; ex[t][d4 + 1] = f.y;
      ex[t][d4 + 2] = f.z; ex[t][d4 + 3] = f.w;
    }
  }
  if (lane == 0) {
#pragma unroll
    for (int t = 0; t < G; t++)
#pragma unroll
      for (int d = 0; d < DD; d++) sL[(wave * G + t) * DD + d] = ex[t][d];
  }

  for (int step = 0; step < n_steps - 1; step++) {
    const float tbase = (float)step * dt;
#pragma unroll 1
    for (int half = 0; half < 2; half++) {
      const float tt = tbase + (half ? 0.5f * dt : 0.0f);
      float acc[G][DD];
      float l[G];
#pragma unroll
      for (int t = 0; t < G; t++) {
        l[t] = 0.f;
#pragma unroll
        for (int d = 0; d < DD; d++) acc[t][d] = 0.f;
      }
#pragma unroll 1
      for (int c = 0; c < NCHUNK; c++) {
        __syncthreads();   // protect LDS from previous chunk's readers
        const int v0 = c * VC;
#pragma unroll
        for (int k = 0; k < 16; k++) {
          int j = tid + (k << 8);
          int row = j >> 8;
          int col = (j & 255) << 2;
          *(float4*)(wL + row * VC + col) =
              *(const float4*)(Wm + (size_t)row * VV + v0 + col);
        }
#pragma unroll
        for (int k = 0; k < 16; k++) {
          int j = tid + (k << 8);
          int row = j >> 8;
          int col = (j & 255) << 2;
          *(float4*)(cL + row * VC + col) =
              *(const float4*)(cbT + (size_t)row * VV + v0 + col);
        }
        {
          int col = tid << 2;
          *(float4*)(b1L + col) = *(const float4*)(B1 + v0 + col);
          *(float4*)(t1L + col) = *(const float4*)(T1 + v0 + col);
        }
        __syncthreads();
#pragma unroll 1
        for (int p = 0; p < 4; p++) {
          const int vb = (p << 8) + (lane << 2);   // 4 consecutive codes / lane
          float e[G][4];
#pragma unroll
          for (int t = 0; t < G; t++)
#pragma unroll
            for (int j = 0; j < 4; j++) e[t][j] = 0.f;
#pragma unroll
          for (int d = 0; d < DD; d++) {
            float4 w4 = *(const float4*)(wL + d * VC + vb);
#pragma unroll
            for (int t = 0; t < G; t++) {
              e[t][0] = fmaf(ex[t][d], w4.x, e[t][0]);
              e[t][1] = fmaf(ex[t][d], w4.y, e[t][1]);
              e[t][2] = fmaf(ex[t][d], w4.z, e[t][2]);
              e[t][3] = fmaf(ex[t][d], w4.w, e[t][3]);
            }
          }
          float4 bb = *(const float4*)(b1L + vb);
          float4 tb = *(const float4*)(t1L + vb);
          const float bias0 = fmaf(tt, tb.x, bb.x);
          const float bias1 = fmaf(tt, tb.y, bb.y);
          const float bias2 = fmaf(tt, tb.z, bb.z);
          const float bias3 = fmaf(tt, tb.w, bb.w);
#pragma unroll
          for (int t = 0; t < G; t++) {
            e[t][0] = exp2f(fmaf(e[t][0], KS, bias0));
            e[t][1] = exp2f(fmaf(e[t][1], KS, bias1));
            e[t][2] = exp2f(fmaf(e[t][2], KS, bias2));
            e[t][3] = exp2f(fmaf(e[t][3], KS, bias3));
            l[t] += (e[t][0] + e[t][1]) + (e[t][2] + e[t][3]);
          }
#pragma unroll
          for (int d = 0; d < DD; d++) {
            float4 c4 = *(const float4*)(cL + d * VC + vb);
#pragma unroll
            for (int t = 0; t < G; t++) {
              acc[t][d] = fmaf(e[t][0], c4.x, acc[t][d]);
              acc[t][d] = fmaf(e[t][1], c4.y, acc[t][d]);
              acc[t][d] = fmaf(e[t][2], c4.z, acc[t][d]);
              acc[t][d] = fmaf(e[t][3], c4.w, acc[t][d]);
            }
          }
        }
      }
      // merge partial (l, acc) across the 64 lanes (all lanes end with full sums)
#pragma unroll
      for (int m = 1; m < 64; m <<= 1) {
#pragma unroll
        for (int t = 0; t < G; t++) {
          l[t] += __shfl_xor(l[t], m, 64);
#pragma unroll
          for (int d = 0; d < DD; d++) acc[t][d] += __shfl_xor(acc[t][d], m, 64);
        }
      }
      const float inv1 = 1.0f / (1.0f - tt + 1e-10f);
      if (half == 0) {
        const float c1 = 0.5f * dt * inv1;   // xm = s + (dt/2)*v1
#pragma unroll
        for (int t = 0; t < G; t++) {
          const float il = 1.0f / l[t];
#pragma unroll
          for (int d = 0; d < DD; d++) {
            const float mu = acc[t][d] * il;
            ex[t][d] = fmaf(c1, mu - ex[t][d], ex[t][d]);
          }
        }
      } else {
        const float c2 = dt * inv1;          // s' = s + dt*v2, v2 from xm (=ex)
#pragma unroll
        for (int t = 0; t < G; t++) {
          const float il = 1.0f / l[t];
#pragma unroll
          for (int d = 0; d < DD; d++) {
            const float mu = acc[t][d] * il;
            const float sv = sL[(wave * G + t) * DD + d];
            ex[t][d] = fmaf(c2, mu - ex[t][d], sv);
          }
        }
        if (lane == 0) {
#pragma unroll
          for (int t = 0; t < G; t++)
#pragma unroll
            for (int d = 0; d < DD; d++) sL[(wave * G + t) * DD + d] = ex[t][d];
        }
      }
    }
  }

  // ---- VQ argmin: d = ||c||^2 - 2 x.c  (||x||^2 constant per token) ----
  float minv[G];
  int mini[G];
#pragma unroll
  for (int t = 0; t < G; t++) { minv[t] = 3.402823466e38f; mini[t] = 0; }
#pragma unroll 1
  for (int p = 0; p < 32; p++) {
    const int v4 = (p << 8) + (lane << 2);
    float dot[G][4];
#pragma unroll
    for (int t = 0; t < G; t++)
#pragma unroll
      for (int j = 0; j < 4; j++) dot[t][j] = 0.f;
#pragma unroll
    for (int d = 0; d < DD; d++) {
      float4 c4 = *(const float4*)(cbT + (size_t)d * VV + v4);   // L2-resident
#pragma unroll
      for (int t = 0; t < G; t++) {
        dot[t][0] = fmaf(ex[t][d], c4.x, dot[t][0]);
        dot[t][1] = fmaf(ex[t][d], c4.y, dot[t][1]);
        dot[t][2] = fmaf(ex[t][d], c4.z, dot[t][2]);
        dot[t][3] = fmaf(ex[t][d], c4.w, dot[t][3]);
      }
    }
    float4 cc = *(const float4*)(CC2 + v4);
#pragma unroll
    for (int t = 0; t < G; t++) {
      float d0 = fmaf(-2.f, dot[t][0], cc.x);
      float d1 = fmaf(-2.f, dot[t][1], cc.y);
      float d2 = fmaf(-2.f, dot[t][2], cc.z);
      float d3 = fmaf(-2.f, dot[t][3], cc.w);
      if (d0 < minv[t]) { minv[t] = d0; mini[t] = v4 + 0; }
      if (d1 < minv[t]) { minv[t] = d1; mini[t] = v4 + 1; }
      if (d2 < minv[t]) { minv[t] = d2; mini[t] = v4 + 2; }
      if (d3 < minv[t]) { minv[t] = d3; mini[t] = v4 + 3; }
    }
  }
#pragma unroll
  for (int m = 1; m < 64; m <<= 1) {
#pragma unroll
    for (int t = 0; t < G; t++) {
      float ov = __shfl_xor(minv[t], m, 64);
      int oi = __shfl_xor(mini[t], m, 64);
      // ties -> smaller index (numpy argmin first-occurrence semantics)
      if (ov < minv[t] || (ov == minv[t] && oi < mini[t])) {
        minv[t] = ov; mini[t] = oi;
      }
    }
  }

  // ---- outputs (fp32!): x_final (131072 floats) then indices-as-float (8192) ----
#pragma unroll
  for (int t = 0; t < G; t++) {
    if (lane == t) {
      const int tok = tokBase + t;
#pragma unroll
      for (int d = 0; d < DD; d++)
        out[(size_t)tok * DD + d] = ex[t][d];
      out[(size_t)NTOK * DD + tok] = (float)mini[t];
    }
  }
}

extern "C" void kernel_launch(void* const* d_in, const int* in_sizes, int n_in,
                              void* d_out, int out_size, void* d_ws, size_t ws_size,
                              hipStream_t stream) {
  const float* x0 = (const float*)d_in[0];
  const float* cb = (const float*)d_in[1];
  const float* Wm = (const float*)d_in[2];
  const float* bm = (const float*)d_in[3];
  const float* tp = (const float*)d_in[4];
  const int* ns   = (const int*)d_in[5];
  float* ws = (float*)d_ws;               // needs 622592 B
  float* out = (float*)d_out;             // fp32 outputs, concatenated flat

  prep_kernel<<<32, 256, 0, stream>>>(cb, bm, tp, ws);
  flow_kernel<<<256, 256, 0, stream>>>(x0, Wm, ws, ns, out);
}